// Round 1
// baseline (1076.947 us; speedup 1.0000x reference)
//
#include <hip/hip_runtime.h>
#include <math.h>

#define B_ 8
#define K_ 4
#define H_ 256
#define W_ 256
#define HID_ 16
#define DT_ 0.1f
#define STEPS_ 12
#define JITERS_ 8
#define OMEGA_ 0.9f
#define D_MAX_ 2.0f
#define CHI_MAX_ 2.0f
#define K_MAXC_ 1.0f
#define HW_ (H_ * W_)

__device__ __forceinline__ float softplus_f(float x) {
    // stable softplus, matches jax.nn.softplus closely enough (f32)
    return fmaxf(x, 0.0f) + log1pf(expf(-fabsf(x)));
}

// params layout: [0..3] D_all[c], [4] chi, [5] cap_t, [6..9] DT*D[c], [10..13] OMEGA/diag[c]
__global__ void setup_params(const float* __restrict__ D_raw,
                             const float* __restrict__ chi_raw,
                             const float* __restrict__ cap_logit,
                             float* __restrict__ params) {
    if (threadIdx.x == 0) {
        for (int c = 0; c < K_; ++c) {
            float d = fminf(softplus_f(D_raw[c]) + 1e-8f, D_MAX_);
            params[c]      = d;
            params[6 + c]  = DT_ * d;
            params[10 + c] = OMEGA_ / (1.0f + DT_ * d * 4.0f);
        }
        float chi = fminf(softplus_f(chi_raw[0]) + 1e-8f, CHI_MAX_);
        params[4] = chi;
        float ct = 1.0f / (1.0f + expf(-cap_logit[0]));
        params[5] = fminf(fmaxf(ct, 0.001f), 0.95f);
    }
}

// conv1: p0 (B,4,H,W) -> h1 (B,16,H,W), 3x3 SAME (zero pad), relu
__global__ __launch_bounds__(256) void conv1_kernel(const float* __restrict__ p0,
                                                    const float* __restrict__ w1,
                                                    const float* __restrict__ b1,
                                                    float* __restrict__ h1) {
    __shared__ float ws[HID_ * K_ * 9];
    __shared__ float bs[HID_];
    int t = threadIdx.x;
    for (int i = t; i < HID_ * K_ * 9; i += 256) ws[i] = w1[i];
    if (t < HID_) bs[t] = b1[t];
    __syncthreads();
    int b = blockIdx.x / H_;
    int y = blockIdx.x % H_;
    int x = t;
    float acc[HID_];
#pragma unroll
    for (int o = 0; o < HID_; ++o) acc[o] = bs[o];
    for (int ic = 0; ic < K_; ++ic) {
        const float* inp = p0 + (size_t)(b * K_ + ic) * HW_;
        for (int ky = 0; ky < 3; ++ky) {
            int iy = y + ky - 1;
            if (iy < 0 || iy >= H_) continue;
#pragma unroll
            for (int kx = 0; kx < 3; ++kx) {
                int ix = x + kx - 1;
                if (ix < 0 || ix >= W_) continue;
                float v = inp[iy * W_ + ix];
#pragma unroll
                for (int o = 0; o < HID_; ++o)
                    acc[o] = fmaf(ws[(o * K_ + ic) * 9 + ky * 3 + kx], v, acc[o]);
            }
        }
    }
    float* outp = h1 + (size_t)b * HID_ * HW_ + y * W_ + x;
#pragma unroll
    for (int o = 0; o < HID_; ++o)
        outp[(size_t)o * HW_] = fmaxf(acc[o], 0.0f);
}

// conv2 (3x3 SAME, relu) fused with conv3 (1x1) + sigmoid -> k_map (B,H,W)
__global__ __launch_bounds__(256) void conv23_kernel(const float* __restrict__ h1,
                                                     const float* __restrict__ w2,
                                                     const float* __restrict__ b2,
                                                     const float* __restrict__ w3,
                                                     const float* __restrict__ b3,
                                                     float* __restrict__ kmap) {
    __shared__ float ws[HID_ * HID_ * 9];
    __shared__ float bs[HID_];
    __shared__ float w3s[HID_];
    __shared__ float b3s;
    int t = threadIdx.x;
    for (int i = t; i < HID_ * HID_ * 9; i += 256) ws[i] = w2[i];
    if (t < HID_) { bs[t] = b2[t]; w3s[t] = w3[t]; }
    if (t == 0) b3s = b3[0];
    __syncthreads();
    int b = blockIdx.x / H_;
    int y = blockIdx.x % H_;
    int x = t;
    float acc[HID_];
#pragma unroll
    for (int o = 0; o < HID_; ++o) acc[o] = bs[o];
    for (int ic = 0; ic < HID_; ++ic) {
        const float* inp = h1 + (size_t)(b * HID_ + ic) * HW_;
        for (int ky = 0; ky < 3; ++ky) {
            int iy = y + ky - 1;
            if (iy < 0 || iy >= H_) continue;
#pragma unroll
            for (int kx = 0; kx < 3; ++kx) {
                int ix = x + kx - 1;
                if (ix < 0 || ix >= W_) continue;
                float v = inp[iy * W_ + ix];
#pragma unroll
                for (int o = 0; o < HID_; ++o)
                    acc[o] = fmaf(ws[(o * HID_ + ic) * 9 + ky * 3 + kx], v, acc[o]);
            }
        }
    }
    float s = b3s;
#pragma unroll
    for (int o = 0; o < HID_; ++o)
        s += w3s[o] * fmaxf(acc[o], 0.0f);
    float km = 1.0f / (1.0f + expf(-s));
    km = fmaxf(km * K_MAXC_, 1e-6f);
    kmap[(size_t)b * HW_ + y * W_ + x] = km;
}

__global__ __launch_bounds__(256) void init_p_kernel(const float* __restrict__ p0,
                                                     float* __restrict__ p) {
    int i = blockIdx.x * 256 + threadIdx.x;
    // fmaxf: IEEE maxNum -> NaN maps to 0, matches max(nan_to_num(p0),0)
    p[i] = fmaxf(p0[i], 0.0f);
}

// rhs = p + DT*(cross + react); one thread per (b,y,x), all 4 channels
__global__ __launch_bounds__(256) void rhs_kernel(const float* __restrict__ p,
                                                  const float* __restrict__ kmap,
                                                  const float* __restrict__ params,
                                                  const int* __restrict__ tumor_idx,
                                                  float* __restrict__ rhs) {
    int b = blockIdx.x / H_;
    int y = blockIdx.x % H_;
    int x = threadIdx.x;
    float chi = params[4];
    float cap = params[5];
    int ti = tumor_idx[0];
    int xp1 = min(x + 1, W_ - 1);
    int xp2 = min(x + 2, W_ - 1);
    int yp1 = min(y + 1, H_ - 1);
    int yp2 = min(y + 2, H_ - 1);

    float pc[K_], px1[K_], py1[K_];
    float gx0[K_], gx1[K_], gy0[K_], gy1[K_];
    float sgx0 = 0.f, sgx1 = 0.f, sgy0 = 0.f, sgy1 = 0.f;
#pragma unroll
    for (int c = 0; c < K_; ++c) {
        const float* pp = p + (size_t)(b * K_ + c) * HW_;
        float pcv  = pp[y * W_ + x];
        float px1v = pp[y * W_ + xp1];
        float px2v = pp[y * W_ + xp2];
        float py1v = pp[yp1 * W_ + x];
        float py2v = pp[yp2 * W_ + x];
        pc[c] = pcv; px1[c] = px1v; py1[c] = py1v;
        gx0[c] = px1v - pcv;   // gx at (y,x)
        gx1[c] = px2v - px1v;  // gx at (y,xp1)
        gy0[c] = py1v - pcv;   // gy at (y,x)
        gy1[c] = py2v - py1v;  // gy at (yp1,x)
        sgx0 += gx0[c]; sgx1 += gx1[c]; sgy0 += gy0[c]; sgy1 += gy1[c];
    }
    float km = kmap[(size_t)b * HW_ + y * W_ + x];
#pragma unroll
    for (int c = 0; c < K_; ++c) {
        float fx0 = -chi * pc[c]  * (sgx0 - gx0[c]);
        float fx1 = -chi * px1[c] * (sgx1 - gx1[c]);
        float fy0 = -chi * pc[c]  * (sgy0 - gy0[c]);
        float fy1 = -chi * py1[c] * (sgy1 - gy1[c]);
        float cross = (fx0 - fx1) + (fy0 - fy1);
        float react = 0.0f;
        if (c == ti) {
            float pt = fminf(fmaxf(pc[c], 0.0f), 1.0f);
            react = km * pt * (1.0f - pt / cap);
        }
        rhs[(size_t)(b * K_ + c) * HW_ + y * W_ + x] = pc[c] + DT_ * (cross + react);
    }
}

// one damped-Jacobi sweep: xo = xk + (OMEGA/diag)*(rhs - (xk - DT*D*Lap(xk)))
__global__ __launch_bounds__(256) void jacobi_kernel(const float* __restrict__ xk,
                                                     const float* __restrict__ rhs,
                                                     const float* __restrict__ params,
                                                     float* __restrict__ xo) {
    int bc = blockIdx.x / H_;  // b*K + c
    int y  = blockIdx.x % H_;
    int c  = bc % K_;
    int x  = threadIdx.x;
    const float* px = xk + (size_t)bc * HW_;
    float dtD = params[6 + c];
    float wod = params[10 + c];
    int xm = max(x - 1, 0), xp = min(x + 1, W_ - 1);
    int ym = max(y - 1, 0), yp = min(y + 1, H_ - 1);
    float ctr = px[y * W_ + x];
    float lap = px[ym * W_ + x] + px[yp * W_ + x] + px[y * W_ + xm] + px[y * W_ + xp]
                - 4.0f * ctr;
    float r = rhs[(size_t)bc * HW_ + y * W_ + x] - (ctr - dtD * lap);
    xo[(size_t)bc * HW_ + y * W_ + x] = ctr + wod * r;
}

// exact replication of reference project_simplex (K=4), then max(.,0)
__global__ __launch_bounds__(256) void project_kernel(const float* __restrict__ xk,
                                                      float* __restrict__ pout) {
    int b = blockIdx.x / H_;
    int y = blockIdx.x % H_;
    int x = threadIdx.x;
    size_t base = (size_t)b * K_ * HW_ + y * W_ + x;
    float v0 = xk[base + 0 * (size_t)HW_];
    float v1 = xk[base + 1 * (size_t)HW_];
    float v2 = xk[base + 2 * (size_t)HW_];
    float v3 = xk[base + 3 * (size_t)HW_];
    // sort descending (network for 4)
    float u0 = v0, u1 = v1, u2 = v2, u3 = v3, t;
    t = fmaxf(u0, u1); u1 = fminf(u0, u1); u0 = t;
    t = fmaxf(u2, u3); u3 = fminf(u2, u3); u2 = t;
    t = fmaxf(u0, u2); u2 = fminf(u0, u2); u0 = t;
    t = fmaxf(u1, u3); u3 = fminf(u1, u3); u1 = t;
    t = fmaxf(u1, u2); u2 = fminf(u1, u2); u1 = t;
    // cssv = cumsum(u) - 1  (cumsum first, then subtract, to match rounding)
    float cs1 = u0 + u1;
    float cs2 = cs1 + u2;
    float cs3 = cs2 + u3;
    float c0 = u0 - 1.0f;
    float c1 = cs1 - 1.0f;
    float c2 = cs2 - 1.0f;
    float c3 = cs3 - 1.0f;
    // cond[0] = u0 - c0 = 1 > 0 always true; rho = largest j with cond[j]
    int rho = 0;
    if (u1 - c1 / 2.0f > 0.0f) rho = 1;
    if (u2 - c2 / 3.0f > 0.0f) rho = 2;
    if (u3 - c3 / 4.0f > 0.0f) rho = 3;
    int ri = rho - 1; if (ri < 0) ri = 0;   // rho_idx = max(rho-1, 0), in {0,1,2}
    float tau = (ri == 0) ? c0 : (ri == 1) ? (c1 / 2.0f) : (c2 / 3.0f);
    float w0 = fmaxf(v0 - tau, 0.0f);
    float w1 = fmaxf(v1 - tau, 0.0f);
    float w2 = fmaxf(v2 - tau, 0.0f);
    float w3 = fmaxf(v3 - tau, 0.0f);
    float inv = 1.0f / (w0 + w1 + w2 + w3 + 1e-8f);
    pout[base + 0 * (size_t)HW_] = w0 * inv;
    pout[base + 1 * (size_t)HW_] = w1 * inv;
    pout[base + 2 * (size_t)HW_] = w2 * inv;
    pout[base + 3 * (size_t)HW_] = w3 * inv;
}

extern "C" void kernel_launch(void* const* d_in, const int* in_sizes, int n_in,
                              void* d_out, int out_size, void* d_ws, size_t ws_size,
                              hipStream_t stream) {
    const float* p0        = (const float*)d_in[0];
    const float* D_raw     = (const float*)d_in[1];
    const float* chi_raw   = (const float*)d_in[2];
    /* d_in[3] k_tumor_raw: computed but unused in reference */
    const float* cap_logit = (const float*)d_in[4];
    const float* w1        = (const float*)d_in[5];
    const float* b1        = (const float*)d_in[6];
    const float* w2        = (const float*)d_in[7];
    const float* b2        = (const float*)d_in[8];
    const float* w3        = (const float*)d_in[9];
    const float* b3        = (const float*)d_in[10];
    const int*   tumor_idx = (const int*)d_in[11];

    const size_t NP  = (size_t)B_ * K_ * HW_;  // 2,097,152
    const size_t NB  = (size_t)B_ * HW_;       // 524,288
    char* ws = (char*)d_ws;
    float* params = (float*)ws;                           // 64 floats
    float* kmap   = (float*)(ws + 256);                   // 2 MB
    float* X      = (float*)(ws + 256 + NB * sizeof(float));
    float* h1     = X;            // 32 MB during CNN (dead afterwards)
    float* p      = X;            // 8 MB
    float* rhs    = X + NP;       // 8 MB
    float* xa     = X + 2 * NP;   // 8 MB
    float* xb     = X + 3 * NP;   // 8 MB
    float* out    = (float*)d_out;

    setup_params<<<1, 64, 0, stream>>>(D_raw, chi_raw, cap_logit, params);
    conv1_kernel<<<B_ * H_, 256, 0, stream>>>(p0, w1, b1, h1);
    conv23_kernel<<<B_ * H_, 256, 0, stream>>>(h1, w2, b2, w3, b3, kmap);
    init_p_kernel<<<(int)(NP / 256), 256, 0, stream>>>(p0, p);

    for (int s = 0; s < STEPS_; ++s) {
        rhs_kernel<<<B_ * H_, 256, 0, stream>>>(p, kmap, params, tumor_idx, rhs);
        const float* src = p;
        float* dst = xa;
        for (int j = 0; j < JITERS_; ++j) {
            jacobi_kernel<<<B_ * K_ * H_, 256, 0, stream>>>(src, rhs, params, dst);
            src = dst;
            dst = (dst == xa) ? xb : xa;
        }
        float* pn = (s == STEPS_ - 1) ? out : p;
        project_kernel<<<B_ * H_, 256, 0, stream>>>(src, pn);
    }
}

// Round 2
// 664.743 us; speedup vs baseline: 1.6201x; 1.6201x over previous
//
#include <hip/hip_runtime.h>
#include <math.h>

#define B_ 8
#define K4 4
#define H_ 256
#define W_ 256
#define HID_ 16
#define DT_ 0.1f
#define STEPS_ 12
#define OMEGA_ 0.9f
#define D_MAX_ 2.0f
#define CHI_MAX_ 2.0f
#define HW_ (H_ * W_)
#define TS 32

__device__ __forceinline__ int clampi(int v, int lo, int hi) { return min(max(v, lo), hi); }

__device__ __forceinline__ float softplus_f(float x) {
    return fmaxf(x, 0.0f) + log1pf(expf(-fabsf(x)));
}

// params: [0..3] D[c], [4] chi, [5] cap_t, [6..9] DT*D[c], [10..13] OMEGA/diag[c]
__global__ void setup_params(const float* __restrict__ D_raw,
                             const float* __restrict__ chi_raw,
                             const float* __restrict__ cap_logit,
                             float* __restrict__ params) {
    if (threadIdx.x == 0) {
        for (int c = 0; c < K4; ++c) {
            float d = fminf(softplus_f(D_raw[c]) + 1e-8f, D_MAX_);
            params[c]      = d;
            params[6 + c]  = DT_ * d;
            params[10 + c] = OMEGA_ / (1.0f + DT_ * d * 4.0f);
        }
        params[4] = fminf(softplus_f(chi_raw[0]) + 1e-8f, CHI_MAX_);
        float ct = 1.0f / (1.0f + expf(-cap_logit[0]));
        params[5] = fminf(fmaxf(ct, 0.001f), 0.95f);
    }
}

// ---------------- fused CNN: conv1(3x3,relu) -> conv2(3x3,relu) -> 1x1 -> sigmoid ----
// LDS: ps[4][36][40] then hs[16][34][36]
#define PS_(c,ry,rx) smem[((c)*36 + (ry))*40 + (rx)]
#define HSOFF 5760
#define HS_(o,ry,rx) smem[HSOFF + ((o)*34 + (ry))*36 + (rx)]
#define CNN_LDS ((5760 + 19584) * 4)

__global__ __launch_bounds__(512) void cnn_kernel(const float* __restrict__ p0,
                                                  const float* __restrict__ w1,
                                                  const float* __restrict__ b1,
                                                  const float* __restrict__ w2,
                                                  const float* __restrict__ b2,
                                                  const float* __restrict__ w3,
                                                  const float* __restrict__ b3,
                                                  float* __restrict__ kmap) {
    extern __shared__ float smem[];
    const int tid = threadIdx.x;
    const int tx0 = blockIdx.x * TS, ty0 = blockIdx.y * TS, b = blockIdx.z;

    // load p0 tile with halo 2, ZERO pad outside domain (conv SAME semantics)
    for (int i = tid; i < 4 * 36 * 36; i += 512) {
        int c = i / 1296, r = i % 1296;
        int ry = r / 36, rx = r % 36;
        int gy = ty0 + ry - 2, gx = tx0 + rx - 2;
        float v = 0.0f;
        if ((unsigned)gy < 256u && (unsigned)gx < 256u)
            v = p0[(((size_t)b * K4 + c) << 16) + gy * W_ + gx];
        PS_(c, ry, rx) = v;
    }
    __syncthreads();

    // conv1 over rel [-1..32]^2 (weights via wave-uniform global reads -> s_load)
    for (int i = tid; i < 34 * 34; i += 512) {
        int ry = i / 34, rx = i % 34;
        int gy = ty0 + ry - 1, gx = tx0 + rx - 1;
        bool indom = ((unsigned)gy < 256u) && ((unsigned)gx < 256u);
        float acc[HID_];
#pragma unroll
        for (int o = 0; o < HID_; ++o) acc[o] = b1[o];
        for (int ic = 0; ic < K4; ++ic)
            for (int ky = 0; ky < 3; ++ky)
                for (int kx = 0; kx < 3; ++kx) {
                    float v = PS_(ic, ry + ky, rx + kx);
#pragma unroll
                    for (int o = 0; o < HID_; ++o)
                        acc[o] = fmaf(w1[(o * K4 + ic) * 9 + ky * 3 + kx], v, acc[o]);
                }
#pragma unroll
        for (int o = 0; o < HID_; ++o)
            HS_(o, ry, rx) = indom ? fmaxf(acc[o], 0.0f) : 0.0f;
    }
    __syncthreads();

    // conv2 + relu + 1x1 conv3 + sigmoid
    for (int i = tid; i < TS * TS; i += 512) {
        int ry = i / TS, rx = i % TS;
        float acc[HID_];
#pragma unroll
        for (int o = 0; o < HID_; ++o) acc[o] = b2[o];
        for (int ic = 0; ic < HID_; ++ic)
            for (int ky = 0; ky < 3; ++ky)
                for (int kx = 0; kx < 3; ++kx) {
                    float v = HS_(ic, ry + ky, rx + kx);
#pragma unroll
                    for (int o = 0; o < HID_; ++o)
                        acc[o] = fmaf(w2[(o * HID_ + ic) * 9 + ky * 3 + kx], v, acc[o]);
                }
        float s = b3[0];
#pragma unroll
        for (int o = 0; o < HID_; ++o)
            s += w3[o] * fmaxf(acc[o], 0.0f);
        float km = 1.0f / (1.0f + expf(-s));
        km = fmaxf(km, 1e-6f);
        kmap[((size_t)b << 16) + (ty0 + ry) * W_ + tx0 + rx] = km;
    }
}

// ---------------- fused step: rhs + 8 Jacobi + simplex projection ----------------
// LDS: xs[2][4][52][56] (rows rel+9, cols rel+12) then rs[4][48][48] (rel+8)
#define XSN 23296
#define XS_(buf,c,row,x) smem[((((buf)*4 + (c))*52 + (row))*56 + (x))]
#define RS_(c,ry,rx) smem[XSN + ((c)*48 + (ry))*48 + (rx)]
#define STEP_LDS ((23296 + 9216) * 4)

__device__ __forceinline__ void jac_one(float* smem, int cur,
                                        int yc, int yu, int yd, int ix,
                                        bool lm, bool rm,
                                        const float4 rsv[4],
                                        const float dtD[4], const float wod[4]) {
    int nxt = cur ^ 1;
#pragma unroll
    for (int c = 0; c < 4; ++c) {
        const float4 ce = *(const float4*)&XS_(cur, c, yc, ix);
        const float4 up = *(const float4*)&XS_(cur, c, yu, ix);
        const float4 dn = *(const float4*)&XS_(cur, c, yd, ix);
        float lf = XS_(cur, c, yc, ix - 1);
        float rt = XS_(cur, c, yc, ix + 4);
        float l0 = lm ? ce.x : lf;
        float r3 = rm ? ce.w : rt;
        float4 o;
        {
            float lap = up.x + dn.x + l0 + ce.y - 4.0f * ce.x;
            float r = rsv[c].x - (ce.x - dtD[c] * lap);
            o.x = ce.x + wod[c] * r;
        }
        {
            float lap = up.y + dn.y + ce.x + ce.z - 4.0f * ce.y;
            float r = rsv[c].y - (ce.y - dtD[c] * lap);
            o.y = ce.y + wod[c] * r;
        }
        {
            float lap = up.z + dn.z + ce.y + ce.w - 4.0f * ce.z;
            float r = rsv[c].z - (ce.z - dtD[c] * lap);
            o.z = ce.z + wod[c] * r;
        }
        {
            float lap = up.w + dn.w + ce.z + r3 - 4.0f * ce.w;
            float r = rsv[c].w - (ce.w - dtD[c] * lap);
            o.w = ce.w + wod[c] * r;
        }
        *(float4*)&XS_(nxt, c, yc, ix) = o;
    }
}

__global__ __launch_bounds__(512) void step_kernel(const float* __restrict__ pin,
                                                   float* __restrict__ pout,
                                                   const float* __restrict__ kmap,
                                                   const float* __restrict__ params,
                                                   const int* __restrict__ tumor_idx,
                                                   int first) {
    extern __shared__ float smem[];
    const int tid = threadIdx.x;
    const int tx0 = blockIdx.x * TS, ty0 = blockIdx.y * TS, b = blockIdx.z;

    // ---- load p region rel [-8..41]^2 (edge-replicate clamp) into xs[0]
    for (int i = tid; i < 10000; i += 512) {
        int c = i / 2500, r = i % 2500;
        int ry = r / 50, rx = r % 50;
        int gy = clampi(ty0 + ry - 8, 0, 255);
        int gx = clampi(tx0 + rx - 8, 0, 255);
        float v = pin[(((size_t)b * K4 + c) << 16) + gy * W_ + gx];
        if (first) v = fmaxf(v, 0.0f);
        XS_(0, c, ry + 1, rx + 4) = v;
    }
    __syncthreads();

    const float chi = params[4], cap = params[5];
    const int ti = tumor_idx[0];

    // ---- rhs on rel [-8..39]^2 (48x48), exactly the reference formulas
    for (int i = tid; i < 48 * 48; i += 512) {
        int ry = i / 48, rx = i % 48;
        int gy = ty0 + ry - 8, gx = tx0 + rx - 8;
        int cy = clampi(gy, 0, 255), y1 = clampi(gy + 1, 0, 255), y2 = clampi(gy + 2, 0, 255);
        int cx = clampi(gx, 0, 255), x1 = clampi(gx + 1, 0, 255), x2 = clampi(gx + 2, 0, 255);
        int ryc = cy - ty0 + 9, ry1 = y1 - ty0 + 9, ry2 = y2 - ty0 + 9;
        int rxc = cx - tx0 + 12, rx1 = x1 - tx0 + 12, rx2 = x2 - tx0 + 12;
        float pc[4], px1[4], py1[4], g0x[4], g1x[4], g0y[4], g1y[4];
        float s0x = 0.f, s1x = 0.f, s0y = 0.f, s1y = 0.f;
#pragma unroll
        for (int c = 0; c < 4; ++c) {
            float pcv = XS_(0, c, ryc, rxc);
            float a   = XS_(0, c, ryc, rx1);
            float bb  = XS_(0, c, ryc, rx2);
            float d   = XS_(0, c, ry1, rxc);
            float e   = XS_(0, c, ry2, rxc);
            pc[c] = pcv; px1[c] = a; py1[c] = d;
            g0x[c] = a - pcv;  g1x[c] = bb - a;
            g0y[c] = d - pcv;  g1y[c] = e - d;
            s0x += g0x[c]; s1x += g1x[c]; s0y += g0y[c]; s1y += g1y[c];
        }
        float km = kmap[((size_t)b << 16) + cy * W_ + cx];
#pragma unroll
        for (int c = 0; c < 4; ++c) {
            float fx0 = -chi * pc[c]  * (s0x - g0x[c]);
            float fx1 = -chi * px1[c] * (s1x - g1x[c]);
            float fy0 = -chi * pc[c]  * (s0y - g0y[c]);
            float fy1 = -chi * py1[c] * (s1y - g1y[c]);
            float cross = (fx0 - fx1) + (fy0 - fy1);
            float react = 0.0f;
            if (c == ti) {
                float pt = fminf(fmaxf(pc[c], 0.0f), 1.0f);
                react = km * pt * (1.0f - pt / cap);
            }
            RS_(c, ry, rx) = pc[c] + DT_ * (cross + react);
        }
    }
    __syncthreads();

    // ---- 8 damped-Jacobi sweeps, float4-vectorized, rhs in registers
    float dtD[4], wod[4];
#pragma unroll
    for (int c = 0; c < 4; ++c) { dtD[c] = params[6 + c]; wod[c] = params[10 + c]; }

    // item A: always valid (tid < 512 <= 575)
    int ryA = tid / 12, gA = tid % 12;
    int gyA = ty0 + ryA - 8;
    int ycA = ryA + 1;
    int yuA = clampi(gyA - 1, 0, 255) - ty0 + 9;
    int ydA = clampi(gyA + 1, 0, 255) - ty0 + 9;
    int ixA = gA * 4 + 4;
    int gx0A = tx0 + gA * 4 - 8;
    bool lmA = (gx0A == 0), rmA = (gx0A == 252);
    float4 rsvA[4];
#pragma unroll
    for (int c = 0; c < 4; ++c) rsvA[c] = *(const float4*)&RS_(c, ryA, gA * 4);

    // item B: valid for tid < 64
    bool hasB = (tid < 64);
    int itB = tid + 512;
    int ryB = 0, gB = 0, ycB = 1, yuB = 1, ydB = 1, ixB = 4;
    bool lmB = false, rmB = false;
    float4 rsvB[4];
    if (hasB) {
        ryB = itB / 12; gB = itB % 12;
        int gyB = ty0 + ryB - 8;
        ycB = ryB + 1;
        yuB = clampi(gyB - 1, 0, 255) - ty0 + 9;
        ydB = clampi(gyB + 1, 0, 255) - ty0 + 9;
        ixB = gB * 4 + 4;
        int gx0B = tx0 + gB * 4 - 8;
        lmB = (gx0B == 0); rmB = (gx0B == 252);
#pragma unroll
        for (int c = 0; c < 4; ++c) rsvB[c] = *(const float4*)&RS_(c, ryB, gB * 4);
    }

    int cur = 0;
    for (int j = 0; j < 8; ++j) {
        jac_one(smem, cur, ycA, yuA, ydA, ixA, lmA, rmA, rsvA, dtD, wod);
        if (hasB) jac_one(smem, cur, ycB, yuB, ydB, ixB, lmB, rmB, rsvB, dtD, wod);
        __syncthreads();
        cur ^= 1;
    }
    // cur == 0: final xk in xs[0], valid on tile [0..31]^2

    // ---- simplex projection (exact replication of reference) + write out
    for (int i = tid; i < TS * TS; i += 512) {
        int ry = i / TS, rx = i % TS;
        float v0 = XS_(0, 0, ry + 9, rx + 12);
        float v1 = XS_(0, 1, ry + 9, rx + 12);
        float v2 = XS_(0, 2, ry + 9, rx + 12);
        float v3 = XS_(0, 3, ry + 9, rx + 12);
        float u0 = v0, u1 = v1, u2 = v2, u3 = v3, t;
        t = fmaxf(u0, u1); u1 = fminf(u0, u1); u0 = t;
        t = fmaxf(u2, u3); u3 = fminf(u2, u3); u2 = t;
        t = fmaxf(u0, u2); u2 = fminf(u0, u2); u0 = t;
        t = fmaxf(u1, u3); u3 = fminf(u1, u3); u1 = t;
        t = fmaxf(u1, u2); u2 = fminf(u1, u2); u1 = t;
        float cs1 = u0 + u1;
        float cs2 = cs1 + u2;
        float c0 = u0 - 1.0f;
        float c1 = cs1 - 1.0f;
        float c2 = cs2 - 1.0f;
        int rho = 0;
        if (u1 - c1 / 2.0f > 0.0f) rho = 1;
        if (u2 - c2 / 3.0f > 0.0f) rho = 2;
        if (u3 - (cs2 + u3 - 1.0f) / 4.0f > 0.0f) rho = 3;
        int ri = rho - 1; if (ri < 0) ri = 0;
        float tau = (ri == 0) ? c0 : (ri == 1) ? (c1 / 2.0f) : (c2 / 3.0f);
        float w0 = fmaxf(v0 - tau, 0.0f);
        float w1 = fmaxf(v1 - tau, 0.0f);
        float w2 = fmaxf(v2 - tau, 0.0f);
        float w3 = fmaxf(v3 - tau, 0.0f);
        float inv = 1.0f / (w0 + w1 + w2 + w3 + 1e-8f);
        size_t base = (((size_t)b * K4) << 16) + (ty0 + ry) * W_ + tx0 + rx;
        pout[base]             = w0 * inv;
        pout[base + HW_]       = w1 * inv;
        pout[base + 2 * HW_]   = w2 * inv;
        pout[base + 3 * HW_]   = w3 * inv;
    }
}

extern "C" void kernel_launch(void* const* d_in, const int* in_sizes, int n_in,
                              void* d_out, int out_size, void* d_ws, size_t ws_size,
                              hipStream_t stream) {
    const float* p0        = (const float*)d_in[0];
    const float* D_raw     = (const float*)d_in[1];
    const float* chi_raw   = (const float*)d_in[2];
    const float* cap_logit = (const float*)d_in[4];
    const float* w1        = (const float*)d_in[5];
    const float* b1        = (const float*)d_in[6];
    const float* w2        = (const float*)d_in[7];
    const float* b2        = (const float*)d_in[8];
    const float* w3        = (const float*)d_in[9];
    const float* b3        = (const float*)d_in[10];
    const int*   tumor_idx = (const int*)d_in[11];

    const size_t NP = (size_t)B_ * K4 * HW_;
    const size_t NB = (size_t)B_ * HW_;
    char* ws = (char*)d_ws;
    float* params = (float*)ws;
    float* kmap   = (float*)(ws + 256);
    float* pA     = (float*)(ws + 256 + NB * sizeof(float));
    float* pB     = pA + NP;
    float* out    = (float*)d_out;

    hipFuncSetAttribute((const void*)cnn_kernel,
                        hipFuncAttributeMaxDynamicSharedMemorySize, CNN_LDS);
    hipFuncSetAttribute((const void*)step_kernel,
                        hipFuncAttributeMaxDynamicSharedMemorySize, STEP_LDS);

    dim3 grid(W_ / TS, H_ / TS, B_);

    setup_params<<<1, 64, 0, stream>>>(D_raw, chi_raw, cap_logit, params);
    cnn_kernel<<<grid, 512, CNN_LDS, stream>>>(p0, w1, b1, w2, b2, w3, b3, kmap);

    float* bufs[2] = {pA, pB};
    for (int s = 0; s < STEPS_; ++s) {
        const float* pin = (s == 0) ? p0 : bufs[(s - 1) & 1];
        float* pout = (s == STEPS_ - 1) ? out : bufs[s & 1];
        step_kernel<<<grid, 512, STEP_LDS, stream>>>(pin, pout, kmap, params,
                                                     tumor_idx, s == 0 ? 1 : 0);
    }
}

// Round 3
// 606.849 us; speedup vs baseline: 1.7747x; 1.0954x over previous
//
#include <hip/hip_runtime.h>
#include <math.h>

#define B_ 8
#define K4 4
#define H_ 256
#define W_ 256
#define HID_ 16
#define DT_ 0.1f
#define STEPS_ 12
#define OMEGA_ 0.9f
#define D_MAX_ 2.0f
#define CHI_MAX_ 2.0f
#define HW_ (H_ * W_)

__device__ __forceinline__ int clampi(int v, int lo, int hi) { return min(max(v, lo), hi); }

__device__ __forceinline__ float softplus_f(float x) {
    return fmaxf(x, 0.0f) + log1pf(expf(-fabsf(x)));
}

union F4 { float4 v; float f[4]; };

// ---------------- setup: params + weight transpose ----------------
// params: [0..3] D[c], [4] chi, [5] cap_t, [6..9] DT*D[c], [10..13] OMEGA/diag[c]
// w1t[(ic*9+k)*16+o] = w1[(o*4+ic)*9+k]   (576)
// w2t[(ic*9+k)*16+o] = w2[(o*16+ic)*9+k]  (2304)
__global__ void setup_kernel(const float* __restrict__ D_raw,
                             const float* __restrict__ chi_raw,
                             const float* __restrict__ cap_logit,
                             const float* __restrict__ w1,
                             const float* __restrict__ w2,
                             float* __restrict__ params,
                             float* __restrict__ w1t,
                             float* __restrict__ w2t) {
    int tid = threadIdx.x;
    if (tid == 0) {
        for (int c = 0; c < K4; ++c) {
            float d = fminf(softplus_f(D_raw[c]) + 1e-8f, D_MAX_);
            params[c]      = d;
            params[6 + c]  = DT_ * d;
            params[10 + c] = OMEGA_ / (1.0f + DT_ * d * 4.0f);
        }
        params[4] = fminf(softplus_f(chi_raw[0]) + 1e-8f, CHI_MAX_);
        float ct = 1.0f / (1.0f + expf(-cap_logit[0]));
        params[5] = fminf(fmaxf(ct, 0.001f), 0.95f);
    }
    for (int i = tid; i < 576; i += 256) {
        int o = i & 15, rest = i >> 4, ic = rest / 9, k = rest % 9;
        w1t[i] = w1[(o * K4 + ic) * 9 + k];
    }
    for (int i = tid; i < 2304; i += 256) {
        int o = i & 15, rest = i >> 4, ic = rest / 9, k = rest % 9;
        w2t[i] = w2[(o * HID_ + ic) * 9 + k];
    }
}

// ---------------- fused CNN, 16x16 tiles ----------------
#define PS2_(c,ry,rx) csmem[((c)*20 + (ry))*24 + (rx)]
#define HS2_(o,ry,rx) csmem[1920 + ((o)*18 + (ry))*20 + (rx)]

__global__ __launch_bounds__(256) void cnn_kernel(const float* __restrict__ p0,
                                                  const float* __restrict__ w1t,
                                                  const float* __restrict__ b1,
                                                  const float* __restrict__ w2t,
                                                  const float* __restrict__ b2,
                                                  const float* __restrict__ w3,
                                                  const float* __restrict__ b3,
                                                  float* __restrict__ kmap) {
    __shared__ float csmem[1920 + 5760];
    const int tid = threadIdx.x;
    const int tx0 = blockIdx.x * 16, ty0 = blockIdx.y * 16, b = blockIdx.z;

    // p0 tile rel [-2..17]^2, zero-pad outside domain
    for (int i = tid; i < 4 * 20 * 20; i += 256) {
        int c = i / 400, r = i % 400;
        int ry = r / 20, rx = r % 20;
        int gy = ty0 + ry - 2, gx = tx0 + rx - 2;
        float v = 0.0f;
        if ((unsigned)gy < 256u && (unsigned)gx < 256u)
            v = p0[(((size_t)b * K4 + c) << 16) + gy * W_ + gx];
        PS2_(c, ry, rx) = v;
    }
    __syncthreads();

    // conv1 on rel [-1..16]^2 (18x18 items)
    for (int i = tid; i < 18 * 18; i += 256) {
        int iy = i / 18, ixx = i % 18;
        int gy = ty0 + iy - 1, gx = tx0 + ixx - 1;
        bool indom = ((unsigned)gy < 256u) && ((unsigned)gx < 256u);
        float acc[HID_];
#pragma unroll
        for (int o = 0; o < HID_; ++o) acc[o] = b1[o];
        for (int ic = 0; ic < K4; ++ic)
            for (int ky = 0; ky < 3; ++ky)
#pragma unroll
                for (int kx = 0; kx < 3; ++kx) {
                    float v = PS2_(ic, iy + ky, ixx + kx);
                    const float* wp = w1t + (ic * 9 + ky * 3 + kx) * 16;
#pragma unroll
                    for (int o = 0; o < HID_; ++o)
                        acc[o] = fmaf(wp[o], v, acc[o]);
                }
#pragma unroll
        for (int o = 0; o < HID_; ++o)
            HS2_(o, iy, ixx) = indom ? fmaxf(acc[o], 0.0f) : 0.0f;
    }
    __syncthreads();

    // conv2 + relu + 1x1 + sigmoid, one px per thread
    {
        int iy2 = tid >> 4, ix2 = tid & 15;
        float acc[HID_];
#pragma unroll
        for (int o = 0; o < HID_; ++o) acc[o] = b2[o];
        for (int ic = 0; ic < HID_; ++ic)
            for (int ky = 0; ky < 3; ++ky)
#pragma unroll
                for (int kx = 0; kx < 3; ++kx) {
                    float v = HS2_(ic, iy2 + ky, ix2 + kx);
                    const float* wp = w2t + (ic * 9 + ky * 3 + kx) * 16;
#pragma unroll
                    for (int o = 0; o < HID_; ++o)
                        acc[o] = fmaf(wp[o], v, acc[o]);
                }
        float s = b3[0];
#pragma unroll
        for (int o = 0; o < HID_; ++o)
            s += w3[o] * fmaxf(acc[o], 0.0f);
        float km = 1.0f / (1.0f + expf(-s));
        km = fmaxf(km, 1e-6f);
        kmap[((size_t)b << 16) + (ty0 + iy2) * W_ + tx0 + ix2] = km;
    }
}

// ---------------- fused step: rhs(+init) + 8 Jacobi + projection ----------------
// tile 64x32, region x rel [-8..73] (82 cols @ +12 -> ix 4..85, width 88),
//                  y rel [-8..41] (50 rows @ +9 -> row 1..50, height 52)
// XS[2][4][52][88] double-buffered = 146,432 B
#define XS_(buf,c,row,col) smem[(buf)*18304 + ((c)*52 + (row))*88 + (col)]
#define STEP_LDS (2 * 18304 * 4)

__global__ __launch_bounds__(1024) void step_kernel(const float* __restrict__ pin,
                                                    float* __restrict__ pout,
                                                    const float* __restrict__ kmap,
                                                    const float* __restrict__ params,
                                                    const int* __restrict__ tumor_idx,
                                                    int first) {
    extern __shared__ float smem[];
    const int tid = threadIdx.x;
    const int tx0 = blockIdx.x * 64, ty0 = blockIdx.y * 32, b = blockIdx.z;

    // ---- load p region into XS[0]
    for (int i = tid; i < 4 * 50 * 82; i += 1024) {
        int c = i / 4100, r = i % 4100;
        int ry = r / 82, rx = r % 82;
        int gy = clampi(ty0 + ry - 8, 0, 255);
        int gx = clampi(tx0 + rx - 8, 0, 255);
        float v = pin[(((size_t)b * K4 + c) << 16) + gy * W_ + gx];
        if (first) v = fmaxf(v, 0.0f);
        XS_(0, c, ry + 1, rx + 4) = v;
    }
    __syncthreads();

    const bool act = (tid < 960);
    const int ry_it = tid / 20, g = tid % 20;  // 48 rows x 20 strips
    const int gy = ty0 + ry_it - 8;
    const int gx0 = tx0 + 4 * g - 8;
    const int yc = ry_it + 1;
    const int yu = clampi(gy - 1, 0, 255) - ty0 + 9;
    const int yd = clampi(gy + 1, 0, 255) - ty0 + 9;
    const int ix = 4 + 4 * g;
    const bool lm = (gx0 == 0), rm = (gx0 == 252);

    float dtD[4], wod[4];
#pragma unroll
    for (int c = 0; c < 4; ++c) { dtD[c] = params[6 + c]; wod[c] = params[10 + c]; }
    const float chi = params[4], cap = params[5];
    const int ti = tumor_idx[0];

    F4 ce[4], rsv[4];
    if (act) {
#pragma unroll
        for (int c = 0; c < 4; ++c)
            ce[c].v = *(const float4*)&XS_(0, c, yc, ix);

        // ---- rhs for my 4-px strip (reference arithmetic order)
        const int cy = clampi(gy, 0, 255);
        const int y1 = clampi(gy + 1, 0, 255);
        const int y2 = clampi(gy + 2, 0, 255);
        const int rowc = cy - ty0 + 9, row1 = y1 - ty0 + 9, row2 = y2 - ty0 + 9;
#pragma unroll
        for (int k = 0; k < 4; ++k) {
            int gxk = gx0 + k;
            int cx = clampi(gxk, 0, 255);
            int x1 = clampi(gxk + 1, 0, 255);
            int x2 = clampi(gxk + 2, 0, 255);
            int col1 = x1 - tx0 + 12, col2 = x2 - tx0 + 12;
            float pc[4], px1[4], py1[4], g0x[4], g1x[4], g0y[4], g1y[4];
            float s0x = 0.f, s1x = 0.f, s0y = 0.f, s1y = 0.f;
#pragma unroll
            for (int c = 0; c < 4; ++c) {
                float pcv = ce[c].f[k];
                float a   = XS_(0, c, rowc, col1);
                float bb  = XS_(0, c, rowc, col2);
                float d   = XS_(0, c, row1, (cx - tx0 + 12));
                float e   = XS_(0, c, row2, (cx - tx0 + 12));
                pc[c] = pcv; px1[c] = a; py1[c] = d;
                g0x[c] = a - pcv;  g1x[c] = bb - a;
                g0y[c] = d - pcv;  g1y[c] = e - d;
                s0x += g0x[c]; s1x += g1x[c]; s0y += g0y[c]; s1y += g1y[c];
            }
            float km = kmap[((size_t)b << 16) + cy * W_ + cx];
#pragma unroll
            for (int c = 0; c < 4; ++c) {
                float fx0 = -chi * pc[c]  * (s0x - g0x[c]);
                float fx1 = -chi * px1[c] * (s1x - g1x[c]);
                float fy0 = -chi * pc[c]  * (s0y - g0y[c]);
                float fy1 = -chi * py1[c] * (s1y - g1y[c]);
                float cross = (fx0 - fx1) + (fy0 - fy1);
                float react = 0.0f;
                if (c == ti) {
                    float pt = fminf(fmaxf(pc[c], 0.0f), 1.0f);
                    react = km * pt * (1.0f - pt / cap);
                }
                rsv[c].f[k] = pc[c] + DT_ * (cross + react);
            }
        }
    }

    // ---- 8 damped-Jacobi sweeps; center strip lives in ce[] registers
    for (int j = 0; j < 8; ++j) {
        int rb = j & 1;
        F4 o[4];
        if (act) {
#pragma unroll
            for (int c = 0; c < 4; ++c) {
                float4 up = *(const float4*)&XS_(rb, c, yu, ix);
                float4 dn = *(const float4*)&XS_(rb, c, yd, ix);
                float lf = XS_(rb, c, yc, ix - 1);
                float rt = XS_(rb, c, yc, ix + 4);
                float4 cv = ce[c].v;
                float l0 = lm ? cv.x : lf;
                float r3 = rm ? cv.w : rt;
                float4 ov;
                {
                    float lap = up.x + dn.x + l0 + cv.y - 4.0f * cv.x;
                    float r = rsv[c].f[0] - (cv.x - dtD[c] * lap);
                    ov.x = cv.x + wod[c] * r;
                }
                {
                    float lap = up.y + dn.y + cv.x + cv.z - 4.0f * cv.y;
                    float r = rsv[c].f[1] - (cv.y - dtD[c] * lap);
                    ov.y = cv.y + wod[c] * r;
                }
                {
                    float lap = up.z + dn.z + cv.y + cv.w - 4.0f * cv.z;
                    float r = rsv[c].f[2] - (cv.z - dtD[c] * lap);
                    ov.z = cv.z + wod[c] * r;
                }
                {
                    float lap = up.w + dn.w + cv.z + r3 - 4.0f * cv.w;
                    float r = rsv[c].f[3] - (cv.w - dtD[c] * lap);
                    ov.w = cv.w + wod[c] * r;
                }
                o[c].v = ov;
            }
        }
        if (j < 7) {
            if (act) {
#pragma unroll
                for (int c = 0; c < 4; ++c)
                    *(float4*)&XS_((rb ^ 1), c, yc, ix) = o[c].v;
            }
            __syncthreads();
        }
        if (act) {
#pragma unroll
            for (int c = 0; c < 4; ++c) ce[c].v = o[c].v;
        }
    }

    // ---- simplex projection straight from registers, inner 32x64 only
    if (act && ry_it >= 8 && ry_it < 40 && g >= 2 && g < 18) {
        F4 res[4];
#pragma unroll
        for (int k = 0; k < 4; ++k) {
            float v0 = ce[0].f[k], v1 = ce[1].f[k], v2 = ce[2].f[k], v3 = ce[3].f[k];
            float u0 = v0, u1 = v1, u2 = v2, u3 = v3, t;
            t = fmaxf(u0, u1); u1 = fminf(u0, u1); u0 = t;
            t = fmaxf(u2, u3); u3 = fminf(u2, u3); u2 = t;
            t = fmaxf(u0, u2); u2 = fminf(u0, u2); u0 = t;
            t = fmaxf(u1, u3); u3 = fminf(u1, u3); u1 = t;
            t = fmaxf(u1, u2); u2 = fminf(u1, u2); u1 = t;
            float cs1 = u0 + u1;
            float cs2 = cs1 + u2;
            float c0 = u0 - 1.0f;
            float c1 = cs1 - 1.0f;
            float c2 = cs2 - 1.0f;
            int rho = 0;
            if (u1 - c1 / 2.0f > 0.0f) rho = 1;
            if (u2 - c2 / 3.0f > 0.0f) rho = 2;
            if (u3 - (cs2 + u3 - 1.0f) / 4.0f > 0.0f) rho = 3;
            int ri = rho - 1; if (ri < 0) ri = 0;
            float tau = (ri == 0) ? c0 : (ri == 1) ? (c1 / 2.0f) : (c2 / 3.0f);
            float w0 = fmaxf(v0 - tau, 0.0f);
            float w1 = fmaxf(v1 - tau, 0.0f);
            float w2 = fmaxf(v2 - tau, 0.0f);
            float w3 = fmaxf(v3 - tau, 0.0f);
            float inv = 1.0f / (w0 + w1 + w2 + w3 + 1e-8f);
            res[0].f[k] = w0 * inv;
            res[1].f[k] = w1 * inv;
            res[2].f[k] = w2 * inv;
            res[3].f[k] = w3 * inv;
        }
        int oy = ty0 + ry_it - 8;
        int ox = tx0 + 4 * g - 8;
#pragma unroll
        for (int c = 0; c < 4; ++c)
            *(float4*)&pout[(((size_t)b * K4 + c) << 16) + oy * W_ + ox] = res[c].v;
    }
}

extern "C" void kernel_launch(void* const* d_in, const int* in_sizes, int n_in,
                              void* d_out, int out_size, void* d_ws, size_t ws_size,
                              hipStream_t stream) {
    const float* p0        = (const float*)d_in[0];
    const float* D_raw     = (const float*)d_in[1];
    const float* chi_raw   = (const float*)d_in[2];
    const float* cap_logit = (const float*)d_in[4];
    const float* w1        = (const float*)d_in[5];
    const float* b1        = (const float*)d_in[6];
    const float* w2        = (const float*)d_in[7];
    const float* b2        = (const float*)d_in[8];
    const float* w3        = (const float*)d_in[9];
    const float* b3        = (const float*)d_in[10];
    const int*   tumor_idx = (const int*)d_in[11];

    const size_t NP = (size_t)B_ * K4 * HW_;   // 8 MB of floats
    char* ws = (char*)d_ws;
    float* params = (float*)(ws + 0);
    float* w1t    = (float*)(ws + 1024);
    float* w2t    = (float*)(ws + 4096);
    float* kmap   = (float*)(ws + 16384);                 // 2 MB
    float* pA     = (float*)(ws + 4  * 1024 * 1024);      // 8 MB
    float* pB     = (float*)(ws + 12 * 1024 * 1024);      // 8 MB
    float* out    = (float*)d_out;

    hipFuncSetAttribute((const void*)step_kernel,
                        hipFuncAttributeMaxDynamicSharedMemorySize, STEP_LDS);

    setup_kernel<<<1, 256, 0, stream>>>(D_raw, chi_raw, cap_logit, w1, w2,
                                        params, w1t, w2t);
    dim3 cgrid(16, 16, B_);
    cnn_kernel<<<cgrid, 256, 0, stream>>>(p0, w1t, b1, w2t, b2, w3, b3, kmap);

    dim3 sgrid(4, 8, B_);
    float* bufs[2] = {pA, pB};
    for (int s = 0; s < STEPS_; ++s) {
        const float* pin = (s == 0) ? p0 : bufs[(s - 1) & 1];
        float* pout = (s == STEPS_ - 1) ? out : bufs[s & 1];
        step_kernel<<<sgrid, 1024, STEP_LDS, stream>>>(pin, pout, kmap, params,
                                                       tumor_idx, s == 0 ? 1 : 0);
    }
}